// Round 1
// baseline (1222.453 us; speedup 1.0000x reference)
//
#include <hip/hip_runtime.h>
#include <stdint.h>

#define N_HOST 50000
#define N_FLOW 200000
#define DIM 128
#define DOUTN 32
#define NEDGE 1000000
#define NLAYER 2

typedef __bf16 bf16;
typedef __bf16 bf16x2 __attribute__((ext_vector_type(2)));
typedef __bf16 bf16x4 __attribute__((ext_vector_type(4)));
typedef __bf16 bf16x8 __attribute__((ext_vector_type(8)));
typedef float floatx4 __attribute__((ext_vector_type(4)));

// ---------------- cast f32 -> bf16, 4 elems/thread ----------------
__global__ void cast_f32_bf16_k(const float* __restrict__ in, bf16* __restrict__ out, int n) {
    int i = (blockIdx.x * 256 + threadIdx.x) * 4;
    if (i + 3 < n) {
        float4 v = *(const float4*)(in + i);
        bf16x4 o;
        o[0] = (bf16)v.x; o[1] = (bf16)v.y; o[2] = (bf16)v.z; o[3] = (bf16)v.w;
        *(bf16x4*)(out + i) = o;
    } else {
        for (int j = 0; j < 4 && i + j < n; ++j) out[i + j] = (bf16)in[i + j];
    }
}

// ---------------- CSR build ----------------
__global__ void count_edges_k(const int* __restrict__ dst, int* __restrict__ cnt, int n) {
    int e = blockIdx.x * 256 + threadIdx.x;
    if (e < n) atomicAdd(&cnt[dst[e]], 1);
}

// block scans 1024 counts (256 thr x 4), writes chunk-exclusive scan + block total
__global__ void scan_a(const int* __restrict__ cnt, int* __restrict__ ex,
                       int* __restrict__ btot, int n) {
    __shared__ int sd[256];
    int t = threadIdx.x;
    int base = blockIdx.x * 1024 + t * 4;
    int v0 = (base     < n) ? cnt[base]     : 0;
    int v1 = (base + 1 < n) ? cnt[base + 1] : 0;
    int v2 = (base + 2 < n) ? cnt[base + 2] : 0;
    int v3 = (base + 3 < n) ? cnt[base + 3] : 0;
    int ts = v0 + v1 + v2 + v3;
    int x = ts;
    sd[t] = x; __syncthreads();
    for (int o = 1; o < 256; o <<= 1) {
        int y = (t >= o) ? sd[t - o] : 0;
        __syncthreads();
        x += y; sd[t] = x; __syncthreads();
    }
    if (t == 255) btot[blockIdx.x] = x;
    int run = x - ts;
    if (base     < n) ex[base]     = run; run += v0;
    if (base + 1 < n) ex[base + 1] = run; run += v1;
    if (base + 2 < n) ex[base + 2] = run; run += v2;
    if (base + 3 < n) ex[base + 3] = run;
}

__global__ void scan_b(const int* __restrict__ btot, int* __restrict__ boff, int nb) {
    __shared__ int sd[256];
    int t = threadIdx.x;
    int v = (t < nb) ? btot[t] : 0;
    int x = v;
    sd[t] = x; __syncthreads();
    for (int o = 1; o < 256; o <<= 1) {
        int y = (t >= o) ? sd[t - o] : 0;
        __syncthreads();
        x += y; sd[t] = x; __syncthreads();
    }
    if (t < nb) boff[t] = x - v;
}

__global__ void scan_c(int* __restrict__ ex, const int* __restrict__ boff,
                       int* __restrict__ cur, int n, int total) {
    int base = blockIdx.x * 1024 + threadIdx.x * 4;
    int o = boff[blockIdx.x];
#pragma unroll
    for (int i = 0; i < 4; ++i) {
        int idx = base + i;
        if (idx < n) { int v = ex[idx] + o; ex[idx] = v; cur[idx] = v; }
    }
    if (blockIdx.x == 0 && threadIdx.x == 0) ex[n] = total;
}

__global__ void scatter_k(const int* __restrict__ src, const int* __restrict__ dst,
                          int* cur, int* __restrict__ es, int n) {
    int e = blockIdx.x * 256 + threadIdx.x;
    if (e < n) { int p = atomicAdd(&cur[dst[e]], 1); es[p] = src[e]; }
}

// ---------------- segment mean: one wave per dst row ----------------
__global__ void aggregate_mean(const int* __restrict__ rs, const int* __restrict__ csr,
                               const bf16x2* __restrict__ x2, bf16x2* __restrict__ m2, int n) {
    int wave = (blockIdx.x << 2) + (threadIdx.x >> 6);
    int lane = threadIdx.x & 63;
    if (wave >= n) return;
    int s0 = rs[wave], s1 = rs[wave + 1];
    float ax = 0.f, ay = 0.f;
    for (int e = s0; e < s1; ++e) {
        int s = csr[e];
        bf16x2 v = x2[s * 64 + lane];
        ax += (float)v.x; ay += (float)v.y;
    }
    int deg = s1 - s0;
    float inv = 1.0f / (float)(deg > 0 ? deg : 1);
    bf16x2 o;
    o.x = (bf16)(ax * inv); o.y = (bf16)(ay * inv);
    m2[wave * 64 + lane] = o;
}

// ---------------- fused dual GEMM + bias + leaky_relu ----------------
// out[r][c] = lrelu( sum_k A1[r][k] W1[k][c] + sum_k A2[r][k] W2[k][c] + b1[c] + b2[c] )
// one wave computes a 16x16 tile; block = 4 waves side by side in N; grid.y=2 covers N=128
__global__ __launch_bounds__(256)
void gemm_dual_lrelu(const bf16* __restrict__ A1, const bf16* __restrict__ A2,
                     const bf16* __restrict__ W1, const bf16* __restrict__ W2,
                     const float* __restrict__ b1, const float* __restrict__ b2,
                     bf16* __restrict__ out, int M) {
    int lane = threadIdx.x & 63;
    int wv = threadIdx.x >> 6;
    int m = lane & 15, quad = lane >> 4;
    int row0 = blockIdx.x << 4;
    int col0 = ((blockIdx.y << 2) + wv) << 4;
    floatx4 acc = {0.f, 0.f, 0.f, 0.f};
#pragma unroll
    for (int k0 = 0; k0 < DIM; k0 += 32) {
        bf16x8 a = *(const bf16x8*)(A1 + (row0 + m) * DIM + k0 + quad * 8);
        bf16x8 b;
#pragma unroll
        for (int j = 0; j < 8; ++j) b[j] = W1[(k0 + quad * 8 + j) * DIM + col0 + m];
        acc = __builtin_amdgcn_mfma_f32_16x16x32_bf16(a, b, acc, 0, 0, 0);
    }
#pragma unroll
    for (int k0 = 0; k0 < DIM; k0 += 32) {
        bf16x8 a = *(const bf16x8*)(A2 + (row0 + m) * DIM + k0 + quad * 8);
        bf16x8 b;
#pragma unroll
        for (int j = 0; j < 8; ++j) b[j] = W2[(k0 + quad * 8 + j) * DIM + col0 + m];
        acc = __builtin_amdgcn_mfma_f32_16x16x32_bf16(a, b, acc, 0, 0, 0);
    }
    int col = col0 + m;
    float bias = b1[col] + b2[col];
#pragma unroll
    for (int r = 0; r < 4; ++r) {
        float v = acc[r] + bias;
        v = v > 0.f ? v : 0.01f * v;
        out[(row0 + quad * 4 + r) * DIM + col] = (bf16)v;
    }
}

// ---------------- final projection: out = A @ Wout + bout (f32 out) ----------------
__global__ __launch_bounds__(128)
void gemm_out_k(const bf16* __restrict__ A, const bf16* __restrict__ W,
                const float* __restrict__ bias, float* __restrict__ out, int M) {
    int lane = threadIdx.x & 63;
    int wv = threadIdx.x >> 6;   // 0..1 -> col tiles of 16 -> N=32
    int m = lane & 15, quad = lane >> 4;
    int row0 = blockIdx.x << 4;
    int col0 = wv << 4;
    floatx4 acc = {0.f, 0.f, 0.f, 0.f};
#pragma unroll
    for (int k0 = 0; k0 < DIM; k0 += 32) {
        bf16x8 a = *(const bf16x8*)(A + (row0 + m) * DIM + k0 + quad * 8);
        bf16x8 b;
#pragma unroll
        for (int j = 0; j < 8; ++j) b[j] = W[(k0 + quad * 8 + j) * DOUTN + col0 + m];
        acc = __builtin_amdgcn_mfma_f32_16x16x32_bf16(a, b, acc, 0, 0, 0);
    }
    int col = col0 + m;
    float bb = bias[col];
#pragma unroll
    for (int r = 0; r < 4; ++r) out[(row0 + quad * 4 + r) * DOUTN + col] = acc[r] + bb;
}

extern "C" void kernel_launch(void* const* d_in, const int* in_sizes, int n_in,
                              void* d_out, int out_size, void* d_ws, size_t ws_size,
                              hipStream_t stream) {
    (void)in_sizes; (void)n_in; (void)out_size; (void)ws_size;
    const float* x_host  = (const float*)d_in[0];
    const float* x_flow  = (const float*)d_in[1];
    const int*   ehf_src = (const int*)d_in[2];
    const int*   ehf_dst = (const int*)d_in[3];
    const int*   efh_src = (const int*)d_in[4];
    const int*   efh_dst = (const int*)d_in[5];
    const float* Wl      = (const float*)d_in[6];
    const float* bl      = (const float*)d_in[7];
    const float* Wr      = (const float*)d_in[8];
    const float* br      = (const float*)d_in[9];
    const float* W_out   = (const float*)d_in[10];
    const float* b_out   = (const float*)d_in[11];
    float* out = (float*)d_out;

    char* basep = (char*)d_ws;
    size_t off = 0;
    auto alloc = [&](size_t b) -> void* {
        void* p = basep + off;
        off += (b + 255) & ~(size_t)255;
        return p;
    };

    bf16* fA    = (bf16*)alloc((size_t)N_FLOW * DIM * 2);
    bf16* fB    = (bf16*)alloc((size_t)N_FLOW * DIM * 2);
    bf16* hA    = (bf16*)alloc((size_t)N_HOST * DIM * 2);
    bf16* hB    = (bf16*)alloc((size_t)N_HOST * DIM * 2);
    bf16* meanF = (bf16*)alloc((size_t)N_FLOW * DIM * 2);
    bf16* meanH = (bf16*)alloc((size_t)N_HOST * DIM * 2);
    bf16* WlB   = (bf16*)alloc((size_t)NLAYER * 2 * DIM * DIM * 2);
    bf16* WrB   = (bf16*)alloc((size_t)NLAYER * 2 * DIM * DIM * 2);
    bf16* WoB   = (bf16*)alloc((size_t)DIM * DOUTN * 2);
    int* rsF  = (int*)alloc((size_t)(N_FLOW + 1) * 4);
    int* curF = (int*)alloc((size_t)N_FLOW * 4);
    int* esF  = (int*)alloc((size_t)NEDGE * 4);
    int* rsH  = (int*)alloc((size_t)(N_HOST + 1) * 4);
    int* curH = (int*)alloc((size_t)N_HOST * 4);
    int* esH  = (int*)alloc((size_t)NEDGE * 4);
    int* btot = (int*)alloc(256 * 4);
    int* boff = (int*)alloc(256 * 4);

    // casts: activations + weights -> bf16
    {
        int n = N_FLOW * DIM;
        cast_f32_bf16_k<<<(n / 4 + 255) / 256, 256, 0, stream>>>(x_flow, fA, n);
        n = N_HOST * DIM;
        cast_f32_bf16_k<<<(n / 4 + 255) / 256, 256, 0, stream>>>(x_host, hA, n);
        n = NLAYER * 2 * DIM * DIM;
        cast_f32_bf16_k<<<(n / 4 + 255) / 256, 256, 0, stream>>>(Wl, WlB, n);
        cast_f32_bf16_k<<<(n / 4 + 255) / 256, 256, 0, stream>>>(Wr, WrB, n);
        n = DIM * DOUTN;
        cast_f32_bf16_k<<<(n / 4 + 255) / 256, 256, 0, stream>>>(W_out, WoB, n);
    }

    // CSR build for both directions (counts live in cursor buffer, overwritten by scan_c)
    auto build_csr = [&](const int* src, const int* dst, int n, int* rs, int* cur, int* es) {
        hipMemsetAsync(cur, 0, (size_t)n * 4, stream);
        count_edges_k<<<(NEDGE + 255) / 256, 256, 0, stream>>>(dst, cur, NEDGE);
        int nb = (n + 1023) / 1024;
        scan_a<<<nb, 256, 0, stream>>>(cur, rs, btot, n);
        scan_b<<<1, 256, 0, stream>>>(btot, boff, nb);
        scan_c<<<nb, 256, 0, stream>>>(rs, boff, cur, n, NEDGE);
        scatter_k<<<(NEDGE + 255) / 256, 256, 0, stream>>>(src, dst, cur, es, NEDGE);
    };
    build_csr(ehf_src, ehf_dst, N_FLOW, rsF, curF, esF);
    build_csr(efh_src, efh_dst, N_HOST, rsH, curH, esH);

    // layers
    bf16 *fc = fA, *fn = fB, *hc = hA, *hn = hB;
    for (int l = 0; l < NLAYER; ++l) {
        aggregate_mean<<<(N_FLOW + 3) / 4, 256, 0, stream>>>(
            rsF, esF, (const bf16x2*)hc, (bf16x2*)meanF, N_FLOW);
        aggregate_mean<<<(N_HOST + 3) / 4, 256, 0, stream>>>(
            rsH, esH, (const bf16x2*)fc, (bf16x2*)meanH, N_HOST);
        gemm_dual_lrelu<<<dim3(N_FLOW / 16, 2), 256, 0, stream>>>(
            meanF, fc, WlB + (l * 2 + 0) * DIM * DIM, WrB + (l * 2 + 0) * DIM * DIM,
            bl + (l * 2 + 0) * DIM, br + (l * 2 + 0) * DIM, fn, N_FLOW);
        gemm_dual_lrelu<<<dim3(N_HOST / 16, 2), 256, 0, stream>>>(
            meanH, hc, WlB + (l * 2 + 1) * DIM * DIM, WrB + (l * 2 + 1) * DIM * DIM,
            bl + (l * 2 + 1) * DIM, br + (l * 2 + 1) * DIM, hn, N_HOST);
        bf16* t = fc; fc = fn; fn = t;
        t = hc; hc = hn; hn = t;
    }

    // final projection
    gemm_out_k<<<N_FLOW / 16, 128, 0, stream>>>(fc, WoB, b_out, out, N_FLOW);
}

// Round 2
// 740.701 us; speedup vs baseline: 1.6504x; 1.6504x over previous
//
#include <hip/hip_runtime.h>
#include <stdint.h>

#define N_HOST 50000
#define N_FLOW 200000
#define DIM 128
#define DOUTN 32
#define NEDGE 1000000
#define NLAYER 2

typedef __bf16 bf16;
typedef __bf16 bf16x4 __attribute__((ext_vector_type(4)));
typedef __bf16 bf16x8 __attribute__((ext_vector_type(8)));
typedef float floatx4 __attribute__((ext_vector_type(4)));

// ---------------- cast f32 -> bf16, 4 elems/thread ----------------
__global__ void cast_f32_bf16_k(const float* __restrict__ in, bf16* __restrict__ out, int n) {
    int i = (blockIdx.x * 256 + threadIdx.x) * 4;
    if (i + 3 < n) {
        float4 v = *(const float4*)(in + i);
        bf16x4 o;
        o[0] = (bf16)v.x; o[1] = (bf16)v.y; o[2] = (bf16)v.z; o[3] = (bf16)v.w;
        *(bf16x4*)(out + i) = o;
    } else {
        for (int j = 0; j < 4 && i + j < n; ++j) out[i + j] = (bf16)in[i + j];
    }
}

// ---------------- weight repack: f32 [128x128] -> bf16 MFMA B-fragment layout ----
// frag index ((ct*4 + k0q)*64 + lane), elem j = W[(k0q*32 + quad*8 + j)*DIM + ct*16 + m]
__global__ void repack_w_k(const float* __restrict__ W, bf16* __restrict__ out) {
    int mat = blockIdx.y;
    int w = blockIdx.x * 4 + (threadIdx.x >> 6);   // 0..31
    int lane = threadIdx.x & 63;
    int ct = w >> 2, k0q = w & 3;
    int quad = lane >> 4, m = lane & 15;
    const float* Wm = W + (size_t)mat * DIM * DIM;
    bf16* om = out + (size_t)mat * DIM * DIM;
    bf16x8 o;
#pragma unroll
    for (int j = 0; j < 8; ++j) o[j] = (bf16)Wm[(k0q * 32 + quad * 8 + j) * DIM + ct * 16 + m];
    *(bf16x8*)(om + ((ct * 4 + k0q) * 64 + lane) * 8) = o;
}

// W_out: f32 [128x32] -> frag layout (2 col tiles)
__global__ void repack_wout_k(const float* __restrict__ W, bf16* __restrict__ out) {
    int w = blockIdx.x * 4 + (threadIdx.x >> 6);   // 0..7
    int lane = threadIdx.x & 63;
    int ct = w >> 2, k0q = w & 3;
    int quad = lane >> 4, m = lane & 15;
    bf16x8 o;
#pragma unroll
    for (int j = 0; j < 8; ++j) o[j] = (bf16)W[(k0q * 32 + quad * 8 + j) * DOUTN + ct * 16 + m];
    *(bf16x8*)(out + ((ct * 4 + k0q) * 64 + lane) * 8) = o;
}

// ---------------- CSR build ----------------
__global__ void count_edges_k(const int* __restrict__ dst, int* __restrict__ cnt, int n) {
    int e = blockIdx.x * 256 + threadIdx.x;
    if (e < n) atomicAdd(&cnt[dst[e]], 1);
}

__global__ void scan_a(const int* __restrict__ cnt, int* __restrict__ ex,
                       int* __restrict__ btot, int n) {
    __shared__ int sd[256];
    int t = threadIdx.x;
    int base = blockIdx.x * 1024 + t * 4;
    int v0 = (base     < n) ? cnt[base]     : 0;
    int v1 = (base + 1 < n) ? cnt[base + 1] : 0;
    int v2 = (base + 2 < n) ? cnt[base + 2] : 0;
    int v3 = (base + 3 < n) ? cnt[base + 3] : 0;
    int ts = v0 + v1 + v2 + v3;
    int x = ts;
    sd[t] = x; __syncthreads();
    for (int o = 1; o < 256; o <<= 1) {
        int y = (t >= o) ? sd[t - o] : 0;
        __syncthreads();
        x += y; sd[t] = x; __syncthreads();
    }
    if (t == 255) btot[blockIdx.x] = x;
    int run = x - ts;
    if (base     < n) ex[base]     = run; run += v0;
    if (base + 1 < n) ex[base + 1] = run; run += v1;
    if (base + 2 < n) ex[base + 2] = run; run += v2;
    if (base + 3 < n) ex[base + 3] = run;
}

__global__ void scan_b(const int* __restrict__ btot, int* __restrict__ boff, int nb) {
    __shared__ int sd[256];
    int t = threadIdx.x;
    int v = (t < nb) ? btot[t] : 0;
    int x = v;
    sd[t] = x; __syncthreads();
    for (int o = 1; o < 256; o <<= 1) {
        int y = (t >= o) ? sd[t - o] : 0;
        __syncthreads();
        x += y; sd[t] = x; __syncthreads();
    }
    if (t < nb) boff[t] = x - v;
}

__global__ void scan_c(int* __restrict__ ex, const int* __restrict__ boff,
                       int* __restrict__ cur, int n, int total) {
    int base = blockIdx.x * 1024 + threadIdx.x * 4;
    int o = boff[blockIdx.x];
#pragma unroll
    for (int i = 0; i < 4; ++i) {
        int idx = base + i;
        if (idx < n) { int v = ex[idx] + o; ex[idx] = v; cur[idx] = v; }
    }
    if (blockIdx.x == 0 && threadIdx.x == 0) ex[n] = total;
}

__global__ void scatter_k(const int* __restrict__ src, const int* __restrict__ dst,
                          int* cur, int* __restrict__ es, int n) {
    int e = blockIdx.x * 256 + threadIdx.x;
    if (e < n) { int p = atomicAdd(&cur[dst[e]], 1); es[p] = src[e]; }
}

// ---------------- segment mean: one wave per dst row, 4 edges in flight ----------
// quad q handles edge e+q; 16 lanes x bf16x8 cover the 128-col row; shfl-xor reduce.
__global__ void aggregate_mean_q(const int* __restrict__ rs, const int* __restrict__ csr,
                                 const bf16x8* __restrict__ x8, bf16x8* __restrict__ m8, int n) {
    int wave = (blockIdx.x << 2) + (threadIdx.x >> 6);
    if (wave >= n) return;
    int lane = threadIdx.x & 63;
    int q = lane >> 4, c8 = lane & 15;
    int s0 = rs[wave], s1 = rs[wave + 1];
    float acc[8] = {0.f, 0.f, 0.f, 0.f, 0.f, 0.f, 0.f, 0.f};
    for (int e = s0 + q; e < s1; e += 4) {
        int s = csr[e];
        bf16x8 v = x8[s * 16 + c8];
#pragma unroll
        for (int j = 0; j < 8; ++j) acc[j] += (float)v[j];
    }
#pragma unroll
    for (int j = 0; j < 8; ++j) {
        acc[j] += __shfl_xor(acc[j], 16, 64);
        acc[j] += __shfl_xor(acc[j], 32, 64);
    }
    if (q == 0) {
        int deg = s1 - s0;
        float inv = 1.0f / (float)(deg > 0 ? deg : 1);
        bf16x8 o;
#pragma unroll
        for (int j = 0; j < 8; ++j) o[j] = (bf16)(acc[j] * inv);
        m8[wave * 16 + c8] = o;
    }
}

// ---------------- fused dual GEMM + bias + leaky_relu (B in registers) ----------
// wave owns a 32-col pair (cp), grid-strides over 16-row tiles.
// per tile: 8 dwordx4 A loads + 16 MFMAs.
__global__ __launch_bounds__(256)
void gemm_dual_lrelu2(const bf16* __restrict__ A1, const bf16* __restrict__ A2,
                      const bf16* __restrict__ W1f, const bf16* __restrict__ W2f,
                      const float* __restrict__ b1, const float* __restrict__ b2,
                      bf16* __restrict__ out, int M) {
    int lane = threadIdx.x & 63;
    int gw = blockIdx.x * 4 + (threadIdx.x >> 6);
    int cp = gw & 3;             // col pair: cols [cp*32, cp*32+32)
    int strip = gw >> 2;
    int nstrips = gridDim.x;     // gridDim.x*4 waves / 4 col pairs
    int quad = lane >> 4, m = lane & 15;
    bf16x8 B1[2][4], B2[2][4];
#pragma unroll
    for (int t = 0; t < 2; ++t) {
        int ct = cp * 2 + t;
#pragma unroll
        for (int k = 0; k < 4; ++k) {
            B1[t][k] = *(const bf16x8*)(W1f + ((ct * 4 + k) * 64 + lane) * 8);
            B2[t][k] = *(const bf16x8*)(W2f + ((ct * 4 + k) * 64 + lane) * 8);
        }
    }
    int c0 = (cp * 2) * 16 + m, c1 = (cp * 2 + 1) * 16 + m;
    float bias0 = b1[c0] + b2[c0];
    float bias1 = b1[c1] + b2[c1];
    int nrt = M >> 4;
    for (int rt = strip; rt < nrt; rt += nstrips) {
        int row0 = rt << 4;
        floatx4 acc0 = {0.f, 0.f, 0.f, 0.f}, acc1 = {0.f, 0.f, 0.f, 0.f};
        const bf16* a1p = A1 + (row0 + m) * DIM + quad * 8;
        const bf16* a2p = A2 + (row0 + m) * DIM + quad * 8;
#pragma unroll
        for (int k = 0; k < 4; ++k) {
            bf16x8 a = *(const bf16x8*)(a1p + k * 32);
            acc0 = __builtin_amdgcn_mfma_f32_16x16x32_bf16(a, B1[0][k], acc0, 0, 0, 0);
            acc1 = __builtin_amdgcn_mfma_f32_16x16x32_bf16(a, B1[1][k], acc1, 0, 0, 0);
        }
#pragma unroll
        for (int k = 0; k < 4; ++k) {
            bf16x8 a = *(const bf16x8*)(a2p + k * 32);
            acc0 = __builtin_amdgcn_mfma_f32_16x16x32_bf16(a, B2[0][k], acc0, 0, 0, 0);
            acc1 = __builtin_amdgcn_mfma_f32_16x16x32_bf16(a, B2[1][k], acc1, 0, 0, 0);
        }
#pragma unroll
        for (int r = 0; r < 4; ++r) {
            int row = row0 + quad * 4 + r;
            float v0 = acc0[r] + bias0; v0 = v0 > 0.f ? v0 : 0.01f * v0;
            float v1 = acc1[r] + bias1; v1 = v1 > 0.f ? v1 : 0.01f * v1;
            out[row * DIM + c0] = (bf16)v0;
            out[row * DIM + c1] = (bf16)v1;
        }
    }
}

// ---------------- final projection (B in registers) ----------------
__global__ __launch_bounds__(256)
void gemm_out2(const bf16* __restrict__ A, const bf16* __restrict__ Wf,
               const float* __restrict__ bias, float* __restrict__ out, int M) {
    int lane = threadIdx.x & 63;
    int gw = blockIdx.x * 4 + (threadIdx.x >> 6);
    int ct = gw & 1;
    int strip = gw >> 1;
    int nstrips = gridDim.x * 2;
    int quad = lane >> 4, m = lane & 15;
    bf16x8 B[4];
#pragma unroll
    for (int k = 0; k < 4; ++k) B[k] = *(const bf16x8*)(Wf + ((ct * 4 + k) * 64 + lane) * 8);
    int col = ct * 16 + m;
    float bb = bias[col];
    int nrt = M >> 4;
    for (int rt = strip; rt < nrt; rt += nstrips) {
        int row0 = rt << 4;
        floatx4 acc = {0.f, 0.f, 0.f, 0.f};
        const bf16* ap = A + (row0 + m) * DIM + quad * 8;
#pragma unroll
        for (int k = 0; k < 4; ++k)
            acc = __builtin_amdgcn_mfma_f32_16x16x32_bf16(*(const bf16x8*)(ap + k * 32), B[k], acc, 0, 0, 0);
#pragma unroll
        for (int r = 0; r < 4; ++r) out[(row0 + quad * 4 + r) * DOUTN + col] = acc[r] + bb;
    }
}

extern "C" void kernel_launch(void* const* d_in, const int* in_sizes, int n_in,
                              void* d_out, int out_size, void* d_ws, size_t ws_size,
                              hipStream_t stream) {
    (void)in_sizes; (void)n_in; (void)out_size; (void)ws_size;
    const float* x_host  = (const float*)d_in[0];
    const float* x_flow  = (const float*)d_in[1];
    const int*   ehf_src = (const int*)d_in[2];
    const int*   ehf_dst = (const int*)d_in[3];
    const int*   efh_src = (const int*)d_in[4];
    const int*   efh_dst = (const int*)d_in[5];
    const float* Wl      = (const float*)d_in[6];
    const float* bl      = (const float*)d_in[7];
    const float* Wr      = (const float*)d_in[8];
    const float* br      = (const float*)d_in[9];
    const float* W_out   = (const float*)d_in[10];
    const float* b_out   = (const float*)d_in[11];
    float* out = (float*)d_out;

    char* basep = (char*)d_ws;
    size_t off = 0;
    auto alloc = [&](size_t b) -> void* {
        void* p = basep + off;
        off += (b + 255) & ~(size_t)255;
        return p;
    };

    bf16* fA    = (bf16*)alloc((size_t)N_FLOW * DIM * 2);
    bf16* fB    = (bf16*)alloc((size_t)N_FLOW * DIM * 2);
    bf16* hA    = (bf16*)alloc((size_t)N_HOST * DIM * 2);
    bf16* hB    = (bf16*)alloc((size_t)N_HOST * DIM * 2);
    bf16* meanF = (bf16*)alloc((size_t)N_FLOW * DIM * 2);
    bf16* meanH = (bf16*)alloc((size_t)N_HOST * DIM * 2);
    bf16* WlF   = (bf16*)alloc((size_t)NLAYER * 2 * DIM * DIM * 2);
    bf16* WrF   = (bf16*)alloc((size_t)NLAYER * 2 * DIM * DIM * 2);
    bf16* WoF   = (bf16*)alloc((size_t)DIM * DOUTN * 2);
    int* rsF  = (int*)alloc((size_t)(N_FLOW + 1) * 4);
    int* curF = (int*)alloc((size_t)N_FLOW * 4);
    int* esF  = (int*)alloc((size_t)NEDGE * 4);
    int* rsH  = (int*)alloc((size_t)(N_HOST + 1) * 4);
    int* curH = (int*)alloc((size_t)N_HOST * 4);
    int* esH  = (int*)alloc((size_t)NEDGE * 4);
    int* btot = (int*)alloc(256 * 4);
    int* boff = (int*)alloc(256 * 4);

    // casts (activations) + weight repacks
    {
        int n = N_FLOW * DIM;
        cast_f32_bf16_k<<<(n / 4 + 255) / 256, 256, 0, stream>>>(x_flow, fA, n);
        n = N_HOST * DIM;
        cast_f32_bf16_k<<<(n / 4 + 255) / 256, 256, 0, stream>>>(x_host, hA, n);
        repack_w_k<<<dim3(8, NLAYER * 2), 256, 0, stream>>>(Wl, WlF);
        repack_w_k<<<dim3(8, NLAYER * 2), 256, 0, stream>>>(Wr, WrF);
        repack_wout_k<<<2, 256, 0, stream>>>(W_out, WoF);
    }

    // CSR build for both directions
    auto build_csr = [&](const int* src, const int* dst, int n, int* rs, int* cur, int* es) {
        hipMemsetAsync(cur, 0, (size_t)n * 4, stream);
        count_edges_k<<<(NEDGE + 255) / 256, 256, 0, stream>>>(dst, cur, NEDGE);
        int nb = (n + 1023) / 1024;
        scan_a<<<nb, 256, 0, stream>>>(cur, rs, btot, n);
        scan_b<<<1, 256, 0, stream>>>(btot, boff, nb);
        scan_c<<<nb, 256, 0, stream>>>(rs, boff, cur, n, NEDGE);
        scatter_k<<<(NEDGE + 255) / 256, 256, 0, stream>>>(src, dst, cur, es, NEDGE);
    };
    build_csr(ehf_src, ehf_dst, N_FLOW, rsF, curF, esF);
    build_csr(efh_src, efh_dst, N_HOST, rsH, curH, esH);

    // layer 0
    aggregate_mean_q<<<(N_FLOW + 3) / 4, 256, 0, stream>>>(
        rsF, esF, (const bf16x8*)hA, (bf16x8*)meanF, N_FLOW);
    aggregate_mean_q<<<(N_HOST + 3) / 4, 256, 0, stream>>>(
        rsH, esH, (const bf16x8*)fA, (bf16x8*)meanH, N_HOST);
    gemm_dual_lrelu2<<<1024, 256, 0, stream>>>(
        meanF, fA, WlF + 0 * DIM * DIM, WrF + 0 * DIM * DIM,
        bl + 0 * DIM, br + 0 * DIM, fB, N_FLOW);
    gemm_dual_lrelu2<<<512, 256, 0, stream>>>(
        meanH, hA, WlF + 1 * DIM * DIM, WrF + 1 * DIM * DIM,
        bl + 1 * DIM, br + 1 * DIM, hB, N_HOST);

    // layer 1 (host update is dead: output only needs f — skip aggH/gemmH)
    aggregate_mean_q<<<(N_FLOW + 3) / 4, 256, 0, stream>>>(
        rsF, esF, (const bf16x8*)hB, (bf16x8*)meanF, N_FLOW);
    gemm_dual_lrelu2<<<1024, 256, 0, stream>>>(
        meanF, fB, WlF + 2 * DIM * DIM, WrF + 2 * DIM * DIM,
        bl + 2 * DIM, br + 2 * DIM, fA, N_FLOW);

    // final projection
    gemm_out2<<<512, 256, 0, stream>>>(fA, WoF, b_out, out, N_FLOW);
}

// Round 3
// 670.495 us; speedup vs baseline: 1.8232x; 1.1047x over previous
//
#include <hip/hip_runtime.h>
#include <stdint.h>

#define N_HOST 50000
#define N_FLOW 200000
#define DIM 128
#define DOUTN 32
#define NEDGE 1000000
#define NLAYER 2

#define GSH_F 8                      // flow: 256 dsts/bucket
#define GSH_H 6                      // host: 64 dsts/bucket
#define NB_F ((N_FLOW + (1 << GSH_F) - 1) >> GSH_F)   // 782
#define NB_H ((N_HOST + (1 << GSH_H) - 1) >> GSH_H)   // 782

typedef __bf16 bf16;
typedef __bf16 bf16x4 __attribute__((ext_vector_type(4)));
typedef __bf16 bf16x8 __attribute__((ext_vector_type(8)));
typedef float floatx4 __attribute__((ext_vector_type(4)));

// ---------------- cast f32 -> bf16, 4 elems/thread ----------------
__global__ void cast_f32_bf16_k(const float* __restrict__ in, bf16* __restrict__ out, int n) {
    int i = (blockIdx.x * 256 + threadIdx.x) * 4;
    if (i + 3 < n) {
        float4 v = *(const float4*)(in + i);
        bf16x4 o;
        o[0] = (bf16)v.x; o[1] = (bf16)v.y; o[2] = (bf16)v.z; o[3] = (bf16)v.w;
        *(bf16x4*)(out + i) = o;
    } else {
        for (int j = 0; j < 4 && i + j < n; ++j) out[i + j] = (bf16)in[i + j];
    }
}

// ---------------- weight repack: f32 [128x128] -> bf16 MFMA B-fragment layout ----
__global__ void repack_w_k(const float* __restrict__ W, bf16* __restrict__ out) {
    int mat = blockIdx.y;
    int w = blockIdx.x * 4 + (threadIdx.x >> 6);   // 0..31
    int lane = threadIdx.x & 63;
    int ct = w >> 2, k0q = w & 3;
    int quad = lane >> 4, m = lane & 15;
    const float* Wm = W + (size_t)mat * DIM * DIM;
    bf16* om = out + (size_t)mat * DIM * DIM;
    bf16x8 o;
#pragma unroll
    for (int j = 0; j < 8; ++j) o[j] = (bf16)Wm[(k0q * 32 + quad * 8 + j) * DIM + ct * 16 + m];
    *(bf16x8*)(om + ((ct * 4 + k0q) * 64 + lane) * 8) = o;
}

__global__ void repack_wout_k(const float* __restrict__ W, bf16* __restrict__ out) {
    int w = blockIdx.x * 4 + (threadIdx.x >> 6);   // 0..7
    int lane = threadIdx.x & 63;
    int ct = w >> 2, k0q = w & 3;
    int quad = lane >> 4, m = lane & 15;
    bf16x8 o;
#pragma unroll
    for (int j = 0; j < 8; ++j) o[j] = (bf16)W[(k0q * 32 + quad * 8 + j) * DOUTN + ct * 16 + m];
    *(bf16x8*)(out + ((ct * 4 + k0q) * 64 + lane) * 8) = o;
}

// ---------------- bucketed CSR build ----------------
// Pass A: per-bucket histogram via LDS, 4096 edges/block
__global__ __launch_bounds__(256)
void bucket_count_k(const int* __restrict__ dst, int* __restrict__ bcount,
                    int n, int gsh, int nb) {
    __shared__ int lc[1024];
    int t = threadIdx.x;
    for (int i = t; i < nb; i += 256) lc[i] = 0;
    __syncthreads();
    int base = blockIdx.x * 4096;
    int end = base + 4096; if (end > n) end = n;
    for (int i = base + t; i < end; i += 256)
        atomicAdd(&lc[dst[i] >> gsh], 1);
    __syncthreads();
    for (int i = t; i < nb; i += 256) {
        int v = lc[i];
        if (v) atomicAdd(&bcount[i], v);
    }
}

// Pass B prep: single-block scan of nb (<=1024) bucket counts -> boffs + padded cursors
__global__ __launch_bounds__(256)
void bucket_scan_k(const int* __restrict__ bcount, int* __restrict__ boffs,
                   int* __restrict__ bcur, int nb) {
    __shared__ int sd[256];
    int t = threadIdx.x;
    int v[4]; int ts = 0;
#pragma unroll
    for (int j = 0; j < 4; ++j) { int i = t * 4 + j; v[j] = (i < nb) ? bcount[i] : 0; ts += v[j]; }
    int x = ts;
    sd[t] = x; __syncthreads();
    for (int o = 1; o < 256; o <<= 1) {
        int y = (t >= o) ? sd[t - o] : 0;
        __syncthreads();
        x += y; sd[t] = x; __syncthreads();
    }
    int run = x - ts;
#pragma unroll
    for (int j = 0; j < 4; ++j) {
        int i = t * 4 + j;
        if (i < nb) { boffs[i] = run; bcur[i << 4] = run; }   // bcur padded: 1 line/counter
        run += v[j];
    }
    if (t == 255) boffs[nb] = x;
}

// Pass B: scatter packed keys to bucket regions (frontier-contiguous writes)
__global__ __launch_bounds__(256)
void bucket_scatter_k(const int* __restrict__ src, const int* __restrict__ dst,
                      int* bcur, int* __restrict__ bkey, int n, int gsh) {
    int e = blockIdx.x * 256 + threadIdx.x;
    if (e < n) {
        int d = dst[e];
        int b = d >> gsh;
        int p = atomicAdd(&bcur[b << 4], 1);
        bkey[p] = (src[e] << 8) | (d & ((1 << gsh) - 1));
    }
}

// Pass C: per-bucket LDS counting sort; emits fine CSR offsets rs[] AND sorted es[]
__global__ __launch_bounds__(256)
void bucket_sort_k(const int* __restrict__ boffs, const int* __restrict__ bkey,
                   int* __restrict__ rs, int* __restrict__ es, int gsh) {
    __shared__ int cnts[256];
    __shared__ int sd[256];
    __shared__ int ldsout[2048];
    int b = blockIdx.x, t = threadIdx.x;
    int G = 1 << gsh;
    int base = boffs[b];
    int cnt = boffs[b + 1] - base;
    if (cnt > 2048) cnt = 2048;   // >21 sigma away for random input; memory-safety only
    int keys[8]; int nk = 0;
    for (int i = t; i < cnt; i += 256) keys[nk++] = bkey[base + i];
    cnts[t] = 0;
    __syncthreads();
    for (int j = 0; j < nk; ++j) atomicAdd(&cnts[keys[j] & 255], 1);
    __syncthreads();
    int v = cnts[t];
    int x = v;
    sd[t] = x; __syncthreads();
    for (int o = 1; o < 256; o <<= 1) {
        int y = (t >= o) ? sd[t - o] : 0;
        __syncthreads();
        x += y; sd[t] = x; __syncthreads();
    }
    int ex = x - v;                  // exclusive prefix
    if (t < G) rs[(b << gsh) + t] = base + ex;
    cnts[t] = ex;                    // reuse as cursor
    __syncthreads();
    for (int j = 0; j < nk; ++j) {
        int k = keys[j];
        int p = atomicAdd(&cnts[k & 255], 1);
        ldsout[p] = k >> 8;
    }
    __syncthreads();
    for (int i = t; i < cnt; i += 256) es[base + i] = ldsout[i];
}

// ---------------- segment mean: one wave per dst row, 4 edges in flight ----------
__global__ void aggregate_mean_q(const int* __restrict__ rs, const int* __restrict__ csr,
                                 const bf16x8* __restrict__ x8, bf16x8* __restrict__ m8, int n) {
    int wave = (blockIdx.x << 2) + (threadIdx.x >> 6);
    if (wave >= n) return;
    int lane = threadIdx.x & 63;
    int q = lane >> 4, c8 = lane & 15;
    int s0 = rs[wave], s1 = rs[wave + 1];
    float acc[8] = {0.f, 0.f, 0.f, 0.f, 0.f, 0.f, 0.f, 0.f};
    for (int e = s0 + q; e < s1; e += 4) {
        int s = csr[e];
        bf16x8 v = x8[s * 16 + c8];
#pragma unroll
        for (int j = 0; j < 8; ++j) acc[j] += (float)v[j];
    }
#pragma unroll
    for (int j = 0; j < 8; ++j) {
        acc[j] += __shfl_xor(acc[j], 16, 64);
        acc[j] += __shfl_xor(acc[j], 32, 64);
    }
    if (q == 0) {
        int deg = s1 - s0;
        float inv = 1.0f / (float)(deg > 0 ? deg : 1);
        bf16x8 o;
#pragma unroll
        for (int j = 0; j < 8; ++j) o[j] = (bf16)(acc[j] * inv);
        m8[wave * 16 + c8] = o;
    }
}

// ---------------- fused dual GEMM + bias + leaky_relu (B in registers) ----------
__global__ __launch_bounds__(256)
void gemm_dual_lrelu2(const bf16* __restrict__ A1, const bf16* __restrict__ A2,
                      const bf16* __restrict__ W1f, const bf16* __restrict__ W2f,
                      const float* __restrict__ b1, const float* __restrict__ b2,
                      bf16* __restrict__ out, int M) {
    int lane = threadIdx.x & 63;
    int gw = blockIdx.x * 4 + (threadIdx.x >> 6);
    int cp = gw & 3;
    int strip = gw >> 2;
    int nstrips = gridDim.x;
    int quad = lane >> 4, m = lane & 15;
    bf16x8 B1[2][4], B2[2][4];
#pragma unroll
    for (int t = 0; t < 2; ++t) {
        int ct = cp * 2 + t;
#pragma unroll
        for (int k = 0; k < 4; ++k) {
            B1[t][k] = *(const bf16x8*)(W1f + ((ct * 4 + k) * 64 + lane) * 8);
            B2[t][k] = *(const bf16x8*)(W2f + ((ct * 4 + k) * 64 + lane) * 8);
        }
    }
    int c0 = (cp * 2) * 16 + m, c1 = (cp * 2 + 1) * 16 + m;
    float bias0 = b1[c0] + b2[c0];
    float bias1 = b1[c1] + b2[c1];
    int nrt = M >> 4;
    for (int rt = strip; rt < nrt; rt += nstrips) {
        int row0 = rt << 4;
        floatx4 acc0 = {0.f, 0.f, 0.f, 0.f}, acc1 = {0.f, 0.f, 0.f, 0.f};
        const bf16* a1p = A1 + (row0 + m) * DIM + quad * 8;
        const bf16* a2p = A2 + (row0 + m) * DIM + quad * 8;
#pragma unroll
        for (int k = 0; k < 4; ++k) {
            bf16x8 a = *(const bf16x8*)(a1p + k * 32);
            acc0 = __builtin_amdgcn_mfma_f32_16x16x32_bf16(a, B1[0][k], acc0, 0, 0, 0);
            acc1 = __builtin_amdgcn_mfma_f32_16x16x32_bf16(a, B1[1][k], acc1, 0, 0, 0);
        }
#pragma unroll
        for (int k = 0; k < 4; ++k) {
            bf16x8 a = *(const bf16x8*)(a2p + k * 32);
            acc0 = __builtin_amdgcn_mfma_f32_16x16x32_bf16(a, B2[0][k], acc0, 0, 0, 0);
            acc1 = __builtin_amdgcn_mfma_f32_16x16x32_bf16(a, B2[1][k], acc1, 0, 0, 0);
        }
#pragma unroll
        for (int r = 0; r < 4; ++r) {
            int row = row0 + quad * 4 + r;
            float v0 = acc0[r] + bias0; v0 = v0 > 0.f ? v0 : 0.01f * v0;
            float v1 = acc1[r] + bias1; v1 = v1 > 0.f ? v1 : 0.01f * v1;
            out[row * DIM + c0] = (bf16)v0;
            out[row * DIM + c1] = (bf16)v1;
        }
    }
}

// ---------------- final projection (B in registers) ----------------
__global__ __launch_bounds__(256)
void gemm_out2(const bf16* __restrict__ A, const bf16* __restrict__ Wf,
               const float* __restrict__ bias, float* __restrict__ out, int M) {
    int lane = threadIdx.x & 63;
    int gw = blockIdx.x * 4 + (threadIdx.x >> 6);
    int ct = gw & 1;
    int strip = gw >> 1;
    int nstrips = gridDim.x * 2;
    int quad = lane >> 4, m = lane & 15;
    bf16x8 B[4];
#pragma unroll
    for (int k = 0; k < 4; ++k) B[k] = *(const bf16x8*)(Wf + ((ct * 4 + k) * 64 + lane) * 8);
    int col = ct * 16 + m;
    float bb = bias[col];
    int nrt = M >> 4;
    for (int rt = strip; rt < nrt; rt += nstrips) {
        int row0 = rt << 4;
        floatx4 acc = {0.f, 0.f, 0.f, 0.f};
        const bf16* ap = A + (row0 + m) * DIM + quad * 8;
#pragma unroll
        for (int k = 0; k < 4; ++k)
            acc = __builtin_amdgcn_mfma_f32_16x16x32_bf16(*(const bf16x8*)(ap + k * 32), B[k], acc, 0, 0, 0);
#pragma unroll
        for (int r = 0; r < 4; ++r) out[(row0 + quad * 4 + r) * DOUTN + col] = acc[r] + bb;
    }
}

extern "C" void kernel_launch(void* const* d_in, const int* in_sizes, int n_in,
                              void* d_out, int out_size, void* d_ws, size_t ws_size,
                              hipStream_t stream) {
    (void)in_sizes; (void)n_in; (void)out_size; (void)ws_size;
    const float* x_host  = (const float*)d_in[0];
    const float* x_flow  = (const float*)d_in[1];
    const int*   ehf_src = (const int*)d_in[2];
    const int*   ehf_dst = (const int*)d_in[3];
    const int*   efh_src = (const int*)d_in[4];
    const int*   efh_dst = (const int*)d_in[5];
    const float* Wl      = (const float*)d_in[6];
    const float* bl      = (const float*)d_in[7];
    const float* Wr      = (const float*)d_in[8];
    const float* br      = (const float*)d_in[9];
    const float* W_out   = (const float*)d_in[10];
    const float* b_out   = (const float*)d_in[11];
    float* out = (float*)d_out;

    char* basep = (char*)d_ws;
    size_t off = 0;
    auto alloc = [&](size_t b) -> void* {
        void* p = basep + off;
        off += (b + 255) & ~(size_t)255;
        return p;
    };

    bf16* fA    = (bf16*)alloc((size_t)N_FLOW * DIM * 2);
    bf16* fB    = (bf16*)alloc((size_t)N_FLOW * DIM * 2);
    bf16* hA    = (bf16*)alloc((size_t)N_HOST * DIM * 2);
    bf16* hB    = (bf16*)alloc((size_t)N_HOST * DIM * 2);
    bf16* meanF = (bf16*)alloc((size_t)N_FLOW * DIM * 2);
    bf16* meanH = (bf16*)alloc((size_t)N_HOST * DIM * 2);
    bf16* WlF   = (bf16*)alloc((size_t)NLAYER * 2 * DIM * DIM * 2);
    bf16* WrF   = (bf16*)alloc((size_t)NLAYER * 2 * DIM * DIM * 2);
    bf16* WoF   = (bf16*)alloc((size_t)DIM * DOUTN * 2);

    int* bcountF = (int*)alloc((size_t)NB_F * 4);
    int* boffsF  = (int*)alloc((size_t)(NB_F + 1) * 4);
    int* bcurF   = (int*)alloc((size_t)NB_F * 16 * 4);
    int* bkeyF   = (int*)alloc((size_t)NEDGE * 4);
    int* rsF     = (int*)alloc((size_t)(NB_F * (1 << GSH_F) + 1) * 4);
    int* esF     = (int*)alloc((size_t)NEDGE * 4);
    int* bcountH = (int*)alloc((size_t)NB_H * 4);
    int* boffsH  = (int*)alloc((size_t)(NB_H + 1) * 4);
    int* bcurH   = (int*)alloc((size_t)NB_H * 16 * 4);
    int* bkeyH   = (int*)alloc((size_t)NEDGE * 4);
    int* rsH     = (int*)alloc((size_t)(NB_H * (1 << GSH_H) + 1) * 4);
    int* esH     = (int*)alloc((size_t)NEDGE * 4);

    // casts + weight repacks
    {
        int n = N_FLOW * DIM;
        cast_f32_bf16_k<<<(n / 4 + 255) / 256, 256, 0, stream>>>(x_flow, fA, n);
        n = N_HOST * DIM;
        cast_f32_bf16_k<<<(n / 4 + 255) / 256, 256, 0, stream>>>(x_host, hA, n);
        repack_w_k<<<dim3(8, NLAYER * 2), 256, 0, stream>>>(Wl, WlF);
        repack_w_k<<<dim3(8, NLAYER * 2), 256, 0, stream>>>(Wr, WrF);
        repack_wout_k<<<2, 256, 0, stream>>>(W_out, WoF);
    }

    // bucketed CSR build (both directions)
    auto build_csr = [&](const int* src, const int* dst, int gsh, int nb,
                         int* bcount, int* boffs, int* bcur, int* bkey, int* rs, int* es) {
        hipMemsetAsync(bcount, 0, (size_t)nb * 4, stream);
        bucket_count_k<<<(NEDGE + 4095) / 4096, 256, 0, stream>>>(dst, bcount, NEDGE, gsh, nb);
        bucket_scan_k<<<1, 256, 0, stream>>>(bcount, boffs, bcur, nb);
        bucket_scatter_k<<<(NEDGE + 255) / 256, 256, 0, stream>>>(src, dst, bcur, bkey, NEDGE, gsh);
        bucket_sort_k<<<nb, 256, 0, stream>>>(boffs, bkey, rs, es, gsh);
    };
    build_csr(ehf_src, ehf_dst, GSH_F, NB_F, bcountF, boffsF, bcurF, bkeyF, rsF, esF);
    build_csr(efh_src, efh_dst, GSH_H, NB_H, bcountH, boffsH, bcurH, bkeyH, rsH, esH);

    // layer 0
    aggregate_mean_q<<<(N_FLOW + 3) / 4, 256, 0, stream>>>(
        rsF, esF, (const bf16x8*)hA, (bf16x8*)meanF, N_FLOW);
    aggregate_mean_q<<<(N_HOST + 3) / 4, 256, 0, stream>>>(
        rsH, esH, (const bf16x8*)fA, (bf16x8*)meanH, N_HOST);
    gemm_dual_lrelu2<<<1024, 256, 0, stream>>>(
        meanF, fA, WlF + 0 * DIM * DIM, WrF + 0 * DIM * DIM,
        bl + 0 * DIM, br + 0 * DIM, fB, N_FLOW);
    gemm_dual_lrelu2<<<512, 256, 0, stream>>>(
        meanH, hA, WlF + 1 * DIM * DIM, WrF + 1 * DIM * DIM,
        bl + 1 * DIM, br + 1 * DIM, hB, N_HOST);

    // layer 1 (host update is dead: output only needs f)
    aggregate_mean_q<<<(N_FLOW + 3) / 4, 256, 0, stream>>>(
        rsF, esF, (const bf16x8*)hB, (bf16x8*)meanF, N_FLOW);
    gemm_dual_lrelu2<<<1024, 256, 0, stream>>>(
        meanF, fB, WlF + 2 * DIM * DIM, WrF + 2 * DIM * DIM,
        bl + 2 * DIM, br + 2 * DIM, fA, N_FLOW);

    // final projection
    gemm_out2<<<512, 256, 0, stream>>>(fA, WoF, b_out, out, N_FLOW);
}

// Round 4
// 659.138 us; speedup vs baseline: 1.8546x; 1.0172x over previous
//
#include <hip/hip_runtime.h>
#include <stdint.h>

#define N_HOST 50000
#define N_FLOW 200000
#define DIM 128
#define DOUTN 32
#define NEDGE 1000000
#define NLAYER 2

#define GSH_F 8                      // flow: 256 dsts/bucket
#define GSH_H 6                      // host: 64 dsts/bucket
#define NB_F ((N_FLOW + (1 << GSH_F) - 1) >> GSH_F)   // 782
#define NB_H ((N_HOST + (1 << GSH_H) - 1) >> GSH_H)   // 782

#define LDS_STRIDE 136               // 16 rows x 136 bf16 (272B rows; breaks pow2 banks)

typedef __bf16 bf16;
typedef __bf16 bf16x4 __attribute__((ext_vector_type(4)));
typedef __bf16 bf16x8 __attribute__((ext_vector_type(8)));
typedef float floatx4 __attribute__((ext_vector_type(4)));

// ---------------- cast f32 -> bf16, 4 elems/thread ----------------
__global__ void cast_f32_bf16_k(const float* __restrict__ in, bf16* __restrict__ out, int n) {
    int i = (blockIdx.x * 256 + threadIdx.x) * 4;
    if (i + 3 < n) {
        float4 v = *(const float4*)(in + i);
        bf16x4 o;
        o[0] = (bf16)v.x; o[1] = (bf16)v.y; o[2] = (bf16)v.z; o[3] = (bf16)v.w;
        *(bf16x4*)(out + i) = o;
    } else {
        for (int j = 0; j < 4 && i + j < n; ++j) out[i + j] = (bf16)in[i + j];
    }
}

// ---------------- weight repack: f32 [128x128] -> bf16 MFMA B-fragment layout ----
__global__ void repack_w_k(const float* __restrict__ W, bf16* __restrict__ out) {
    int mat = blockIdx.y;
    int w = blockIdx.x * 4 + (threadIdx.x >> 6);   // 0..31
    int lane = threadIdx.x & 63;
    int ct = w >> 2, k0q = w & 3;
    int quad = lane >> 4, m = lane & 15;
    const float* Wm = W + (size_t)mat * DIM * DIM;
    bf16* om = out + (size_t)mat * DIM * DIM;
    bf16x8 o;
#pragma unroll
    for (int j = 0; j < 8; ++j) o[j] = (bf16)Wm[(k0q * 32 + quad * 8 + j) * DIM + ct * 16 + m];
    *(bf16x8*)(om + ((ct * 4 + k0q) * 64 + lane) * 8) = o;
}

__global__ void repack_wout_k(const float* __restrict__ W, bf16* __restrict__ out) {
    int w = blockIdx.x * 4 + (threadIdx.x >> 6);   // 0..7
    int lane = threadIdx.x & 63;
    int ct = w >> 2, k0q = w & 3;
    int quad = lane >> 4, m = lane & 15;
    bf16x8 o;
#pragma unroll
    for (int j = 0; j < 8; ++j) o[j] = (bf16)W[(k0q * 32 + quad * 8 + j) * DOUTN + ct * 16 + m];
    *(bf16x8*)(out + ((ct * 4 + k0q) * 64 + lane) * 8) = o;
}

// ---------------- bucketed CSR build ----------------
__global__ __launch_bounds__(256)
void bucket_count_k(const int* __restrict__ dst, int* __restrict__ bcount,
                    int n, int gsh, int nb) {
    __shared__ int lc[1024];
    int t = threadIdx.x;
    for (int i = t; i < nb; i += 256) lc[i] = 0;
    __syncthreads();
    int base = blockIdx.x * 4096;
    int end = base + 4096; if (end > n) end = n;
    for (int i = base + t; i < end; i += 256)
        atomicAdd(&lc[dst[i] >> gsh], 1);
    __syncthreads();
    for (int i = t; i < nb; i += 256) {
        int v = lc[i];
        if (v) atomicAdd(&bcount[i], v);
    }
}

__global__ __launch_bounds__(256)
void bucket_scan_k(const int* __restrict__ bcount, int* __restrict__ boffs,
                   int* __restrict__ bcur, int nb) {
    __shared__ int sd[256];
    int t = threadIdx.x;
    int v[4]; int ts = 0;
#pragma unroll
    for (int j = 0; j < 4; ++j) { int i = t * 4 + j; v[j] = (i < nb) ? bcount[i] : 0; ts += v[j]; }
    int x = ts;
    sd[t] = x; __syncthreads();
    for (int o = 1; o < 256; o <<= 1) {
        int y = (t >= o) ? sd[t - o] : 0;
        __syncthreads();
        x += y; sd[t] = x; __syncthreads();
    }
    int run = x - ts;
#pragma unroll
    for (int j = 0; j < 4; ++j) {
        int i = t * 4 + j;
        if (i < nb) { boffs[i] = run; bcur[i << 4] = run; }
        run += v[j];
    }
    if (t == 255) boffs[nb] = x;
}

__global__ __launch_bounds__(256)
void bucket_scatter_k(const int* __restrict__ src, const int* __restrict__ dst,
                      int* bcur, int* __restrict__ bkey, int n, int gsh) {
    int e = blockIdx.x * 256 + threadIdx.x;
    if (e < n) {
        int d = dst[e];
        int b = d >> gsh;
        int p = atomicAdd(&bcur[b << 4], 1);
        bkey[p] = (src[e] << 8) | (d & ((1 << gsh) - 1));
    }
}

__global__ __launch_bounds__(256)
void bucket_sort_k(const int* __restrict__ boffs, const int* __restrict__ bkey,
                   int* __restrict__ rs, int* __restrict__ es, int gsh) {
    __shared__ int cnts[256];
    __shared__ int sd[256];
    __shared__ int ldsout[2048];
    int b = blockIdx.x, t = threadIdx.x;
    int G = 1 << gsh;
    int base = boffs[b];
    int cnt = boffs[b + 1] - base;
    if (cnt > 2048) cnt = 2048;   // memory-safety only (>21 sigma for random input)
    int keys[8]; int nk = 0;
    for (int i = t; i < cnt; i += 256) keys[nk++] = bkey[base + i];
    cnts[t] = 0;
    __syncthreads();
    for (int j = 0; j < nk; ++j) atomicAdd(&cnts[keys[j] & 255], 1);
    __syncthreads();
    int v = cnts[t];
    int x = v;
    sd[t] = x; __syncthreads();
    for (int o = 1; o < 256; o <<= 1) {
        int y = (t >= o) ? sd[t - o] : 0;
        __syncthreads();
        x += y; sd[t] = x; __syncthreads();
    }
    int ex = x - v;
    if (t < G) rs[(b << gsh) + t] = base + ex;
    cnts[t] = ex;
    __syncthreads();
    for (int j = 0; j < nk; ++j) {
        int k = keys[j];
        int p = atomicAdd(&cnts[k & 255], 1);
        ldsout[p] = k >> 8;
    }
    __syncthreads();
    for (int i = t; i < cnt; i += 256) es[base + i] = ldsout[i];
}

// ---------------- plain GEMM: C[M x 128] = A[M x 128] @ W (bf16 out, no bias) ----
__global__ __launch_bounds__(256)
void gemm_plain(const bf16* __restrict__ A, const bf16* __restrict__ Wf,
                bf16* __restrict__ out, int M) {
    int lane = threadIdx.x & 63;
    int gw = blockIdx.x * 4 + (threadIdx.x >> 6);
    int cp = gw & 3;
    int strip = gw >> 2;
    int nstrips = gridDim.x;
    int quad = lane >> 4, m = lane & 15;
    bf16x8 B[2][4];
#pragma unroll
    for (int t = 0; t < 2; ++t) {
        int ct = cp * 2 + t;
#pragma unroll
        for (int k = 0; k < 4; ++k)
            B[t][k] = *(const bf16x8*)(Wf + ((ct * 4 + k) * 64 + lane) * 8);
    }
    int c0 = (cp * 2) * 16 + m, c1 = (cp * 2 + 1) * 16 + m;
    int nrt = M >> 4;
    for (int rt = strip; rt < nrt; rt += nstrips) {
        int row0 = rt << 4;
        floatx4 acc0 = {0.f, 0.f, 0.f, 0.f}, acc1 = {0.f, 0.f, 0.f, 0.f};
        const bf16* ap = A + (row0 + m) * DIM + quad * 8;
#pragma unroll
        for (int k = 0; k < 4; ++k) {
            bf16x8 a = *(const bf16x8*)(ap + k * 32);
            acc0 = __builtin_amdgcn_mfma_f32_16x16x32_bf16(a, B[0][k], acc0, 0, 0, 0);
            acc1 = __builtin_amdgcn_mfma_f32_16x16x32_bf16(a, B[1][k], acc1, 0, 0, 0);
        }
#pragma unroll
        for (int r = 0; r < 4; ++r) {
            int row = row0 + quad * 4 + r;
            out[row * DIM + c0] = (bf16)acc0[r];
            out[row * DIM + c1] = (bf16)acc1[r];
        }
    }
}

// ---------------- fused SAGE layer kernel ----------------
// Per 16-row tile of dst nodes:
//   phase 1: gather-mean of PRE-TRANSFORMED source rows (tW = x_src @ Wl),
//            one 16-lane group per row, result staged in LDS (bf16).
//   phase 2: MFMA x_dst @ Wr; epilogue adds LDS mean + bl + br, leaky_relu, store.
__global__ __launch_bounds__(256)
void fused_sage(const int* __restrict__ rs, const int* __restrict__ csr,
                const bf16x8* __restrict__ tW8,   // [n_src x 16] bf16x8 (pre-transformed)
                const bf16* __restrict__ Xd,      // dst features [n_dst x 128]
                const bf16* __restrict__ Wrf,     // Wr frags
                const float* __restrict__ b1, const float* __restrict__ b2,
                bf16* __restrict__ out) {
    __shared__ bf16 lmean[16 * LDS_STRIDE];
    int lane = threadIdx.x & 63;
    int wv = threadIdx.x >> 6;        // 0..3
    int quad = lane >> 4;             // phase1: row-group; phase2: C-layout quad
    int m = lane & 15;                // phase1: col octet; phase2: C-layout col
    int row0 = blockIdx.x << 4;

    // load B fragments early (held across phase 1)
    bf16x8 B[2][4];
#pragma unroll
    for (int t = 0; t < 2; ++t) {
        int ct = wv * 2 + t;
#pragma unroll
        for (int k = 0; k < 4; ++k)
            B[t][k] = *(const bf16x8*)(Wrf + ((ct * 4 + k) * 64 + lane) * 8);
    }

    // ---- phase 1: gather mean for row (wv*4 + quad) ----
    {
        int lrow = wv * 4 + quad;
        int row = row0 + lrow;
        int s0 = rs[row], s1 = rs[row + 1];
        float acc[8] = {0.f, 0.f, 0.f, 0.f, 0.f, 0.f, 0.f, 0.f};
        for (int e = s0; e < s1; ++e) {
            int s = csr[e];
            bf16x8 v = tW8[s * 16 + m];
#pragma unroll
            for (int j = 0; j < 8; ++j) acc[j] += (float)v[j];
        }
        int deg = s1 - s0;
        float inv = 1.0f / (float)(deg > 0 ? deg : 1);
        bf16x8 o;
#pragma unroll
        for (int j = 0; j < 8; ++j) o[j] = (bf16)(acc[j] * inv);
        *(bf16x8*)(lmean + lrow * LDS_STRIDE + m * 8) = o;
    }
    __syncthreads();

    // ---- phase 2: MFMA Xd @ Wr for cols [wv*32, wv*32+32) ----
    floatx4 acc0 = {0.f, 0.f, 0.f, 0.f}, acc1 = {0.f, 0.f, 0.f, 0.f};
    const bf16* ap = Xd + (row0 + m) * DIM + quad * 8;
#pragma unroll
    for (int k = 0; k < 4; ++k) {
        bf16x8 a = *(const bf16x8*)(ap + k * 32);
        acc0 = __builtin_amdgcn_mfma_f32_16x16x32_bf16(a, B[0][k], acc0, 0, 0, 0);
        acc1 = __builtin_amdgcn_mfma_f32_16x16x32_bf16(a, B[1][k], acc1, 0, 0, 0);
    }
    int c0 = wv * 32 + m, c1 = wv * 32 + 16 + m;
    float bias0 = b1[c0] + b2[c0];
    float bias1 = b1[c1] + b2[c1];
#pragma unroll
    for (int r = 0; r < 4; ++r) {
        int lrow = quad * 4 + r;
        float v0 = acc0[r] + (float)lmean[lrow * LDS_STRIDE + c0] + bias0;
        float v1 = acc1[r] + (float)lmean[lrow * LDS_STRIDE + c1] + bias1;
        v0 = v0 > 0.f ? v0 : 0.01f * v0;
        v1 = v1 > 0.f ? v1 : 0.01f * v1;
        int row = row0 + lrow;
        out[row * DIM + c0] = (bf16)v0;
        out[row * DIM + c1] = (bf16)v1;
    }
}

// ---------------- final projection (B in registers) ----------------
__global__ __launch_bounds__(256)
void gemm_out2(const bf16* __restrict__ A, const bf16* __restrict__ Wf,
               const float* __restrict__ bias, float* __restrict__ out, int M) {
    int lane = threadIdx.x & 63;
    int gw = blockIdx.x * 4 + (threadIdx.x >> 6);
    int ct = gw & 1;
    int strip = gw >> 1;
    int nstrips = gridDim.x * 2;
    int quad = lane >> 4, m = lane & 15;
    bf16x8 B[4];
#pragma unroll
    for (int k = 0; k < 4; ++k) B[k] = *(const bf16x8*)(Wf + ((ct * 4 + k) * 64 + lane) * 8);
    int col = ct * 16 + m;
    float bb = bias[col];
    int nrt = M >> 4;
    for (int rt = strip; rt < nrt; rt += nstrips) {
        int row0 = rt << 4;
        floatx4 acc = {0.f, 0.f, 0.f, 0.f};
        const bf16* ap = A + (row0 + m) * DIM + quad * 8;
#pragma unroll
        for (int k = 0; k < 4; ++k)
            acc = __builtin_amdgcn_mfma_f32_16x16x32_bf16(*(const bf16x8*)(ap + k * 32), B[k], acc, 0, 0, 0);
#pragma unroll
        for (int r = 0; r < 4; ++r) out[(row0 + quad * 4 + r) * DOUTN + col] = acc[r] + bb;
    }
}

extern "C" void kernel_launch(void* const* d_in, const int* in_sizes, int n_in,
                              void* d_out, int out_size, void* d_ws, size_t ws_size,
                              hipStream_t stream) {
    (void)in_sizes; (void)n_in; (void)out_size; (void)ws_size;
    const float* x_host  = (const float*)d_in[0];
    const float* x_flow  = (const float*)d_in[1];
    const int*   ehf_src = (const int*)d_in[2];
    const int*   ehf_dst = (const int*)d_in[3];
    const int*   efh_src = (const int*)d_in[4];
    const int*   efh_dst = (const int*)d_in[5];
    const float* Wl      = (const float*)d_in[6];
    const float* bl      = (const float*)d_in[7];
    const float* Wr      = (const float*)d_in[8];
    const float* br      = (const float*)d_in[9];
    const float* W_out   = (const float*)d_in[10];
    const float* b_out   = (const float*)d_in[11];
    float* out = (float*)d_out;

    char* basep = (char*)d_ws;
    size_t off = 0;
    auto alloc = [&](size_t b) -> void* {
        void* p = basep + off;
        off += (b + 255) & ~(size_t)255;
        return p;
    };

    bf16* fA  = (bf16*)alloc((size_t)N_FLOW * DIM * 2);
    bf16* fB  = (bf16*)alloc((size_t)N_FLOW * DIM * 2);
    bf16* hA  = (bf16*)alloc((size_t)N_HOST * DIM * 2);
    bf16* hB  = (bf16*)alloc((size_t)N_HOST * DIM * 2);
    bf16* hW  = (bf16*)alloc((size_t)N_HOST * DIM * 2);   // h @ Wl  (pre-transformed)
    bf16* fW  = (bf16*)alloc((size_t)N_FLOW * DIM * 2);   // f @ Wl  (pre-transformed)
    bf16* WlF = (bf16*)alloc((size_t)NLAYER * 2 * DIM * DIM * 2);
    bf16* WrF = (bf16*)alloc((size_t)NLAYER * 2 * DIM * DIM * 2);
    bf16* WoF = (bf16*)alloc((size_t)DIM * DOUTN * 2);

    int* bcountF = (int*)alloc((size_t)NB_F * 4);
    int* boffsF  = (int*)alloc((size_t)(NB_F + 1) * 4);
    int* bcurF   = (int*)alloc((size_t)NB_F * 16 * 4);
    int* bkeyF   = (int*)alloc((size_t)NEDGE * 4);
    int* rsF     = (int*)alloc((size_t)(NB_F * (1 << GSH_F) + 1) * 4);
    int* esF     = (int*)alloc((size_t)NEDGE * 4);
    int* bcountH = (int*)alloc((size_t)NB_H * 4);
    int* boffsH  = (int*)alloc((size_t)(NB_H + 1) * 4);
    int* bcurH   = (int*)alloc((size_t)NB_H * 16 * 4);
    int* bkeyH   = (int*)alloc((size_t)NEDGE * 4);
    int* rsH     = (int*)alloc((size_t)(NB_H * (1 << GSH_H) + 1) * 4);
    int* esH     = (int*)alloc((size_t)NEDGE * 4);

    // casts + weight repacks
    {
        int n = N_FLOW * DIM;
        cast_f32_bf16_k<<<(n / 4 + 255) / 256, 256, 0, stream>>>(x_flow, fA, n);
        n = N_HOST * DIM;
        cast_f32_bf16_k<<<(n / 4 + 255) / 256, 256, 0, stream>>>(x_host, hA, n);
        repack_w_k<<<dim3(8, NLAYER * 2), 256, 0, stream>>>(Wl, WlF);
        repack_w_k<<<dim3(8, NLAYER * 2), 256, 0, stream>>>(Wr, WrF);
        repack_wout_k<<<2, 256, 0, stream>>>(W_out, WoF);
    }

    // bucketed CSR build (both directions)
    auto build_csr = [&](const int* src, const int* dst, int gsh, int nb,
                         int* bcount, int* boffs, int* bcur, int* bkey, int* rs, int* es) {
        hipMemsetAsync(bcount, 0, (size_t)nb * 4, stream);
        bucket_count_k<<<(NEDGE + 4095) / 4096, 256, 0, stream>>>(dst, bcount, NEDGE, gsh, nb);
        bucket_scan_k<<<1, 256, 0, stream>>>(bcount, boffs, bcur, nb);
        bucket_scatter_k<<<(NEDGE + 255) / 256, 256, 0, stream>>>(src, dst, bcur, bkey, NEDGE, gsh);
        bucket_sort_k<<<nb, 256, 0, stream>>>(boffs, bkey, rs, es, gsh);
    };
    build_csr(ehf_src, ehf_dst, GSH_F, NB_F, bcountF, boffsF, bcurF, bkeyF, rsF, esF);
    build_csr(efh_src, efh_dst, GSH_H, NB_H, bcountH, boffsH, bcurH, bkeyH, rsH, esH);

    // ---- layer 0 ----
    // pre-transform source tables through lin_l
    gemm_plain<<<512, 256, 0, stream>>>(hA, WlF + 0 * DIM * DIM, hW, N_HOST);   // for flow update
    gemm_plain<<<1024, 256, 0, stream>>>(fA, WlF + 1 * DIM * DIM, fW, N_FLOW);  // for host update
    // fused: mean-gather(tW) + Xd@Wr + biases + lrelu
    fused_sage<<<N_FLOW / 16, 256, 0, stream>>>(
        rsF, esF, (const bf16x8*)hW, fA, WrF + 0 * DIM * DIM,
        bl + 0 * DIM, br + 0 * DIM, fB);
    fused_sage<<<N_HOST / 16, 256, 0, stream>>>(
        rsH, esH, (const bf16x8*)fW, hA, WrF + 1 * DIM * DIM,
        bl + 1 * DIM, br + 1 * DIM, hB);

    // ---- layer 1 (host update is dead: output only needs f) ----
    gemm_plain<<<512, 256, 0, stream>>>(hB, WlF + 2 * DIM * DIM, hW, N_HOST);
    fused_sage<<<N_FLOW / 16, 256, 0, stream>>>(
        rsF, esF, (const bf16x8*)hW, fB, WrF + 2 * DIM * DIM,
        bl + 2 * DIM, br + 2 * DIM, fA);

    // final projection
    gemm_out2<<<512, 256, 0, stream>>>(fA, WoF, b_out, out, N_FLOW);
}